// Round 9
// baseline (146.266 us; speedup 1.0000x reference)
//
#include <hip/hip_runtime.h>
#include <hip/hip_bf16.h>
#include <math.h>

// Problem constants
#define Bdim 2
#define Tdim 512
#define Cdim 256
#define Hdim 8
#define Edim 32
#define NTYPES 16
#define TI 8       // i-tile size
#define JT 128     // j-tile size

// ---------------------------------------------------------------------------
// Kernel 1: fused edge-tables + qkv GEMM.
// blocks 0..383: qkv GEMM (M=1024,K=256,N=768), 32x64 tile, scatter (B,H,T,E)
// blocks 384..399: ekt/evt = emb[t] @ w_edge_{k,v}
// ---------------------------------------------------------------------------
__global__ __launch_bounds__(256) void pre_kernel(
    const float* __restrict__ A, const float* __restrict__ Bw,
    const float* __restrict__ emb, const float* __restrict__ wk,
    const float* __restrict__ wv,
    float* __restrict__ qT, float* __restrict__ kT, float* __restrict__ vT,
    float* __restrict__ ekt, float* __restrict__ evt)
{
    __shared__ float smem[16 * 34 + 16 * 64];
    int tid = threadIdx.x;

    if (blockIdx.x >= 384) {
        int t = blockIdx.x - 384;
        float* se = smem;
        se[tid] = emb[t * Cdim + tid];
        __syncthreads();
        float a = 0.f, b = 0.f;
        for (int k = 0; k < Cdim; ++k) {
            float ev = se[k];
            a = fmaf(ev, wk[k * Cdim + tid], a);
            b = fmaf(ev, wv[k * Cdim + tid], b);
        }
        ekt[t * Cdim + tid] = a;
        evt[t * Cdim + tid] = b;
        return;
    }

    const int N = 3 * Cdim;
    const int K = Cdim;
    float (*As)[34] = (float(*)[34])smem;
    float (*Bs)[64] = (float(*)[64])(smem + 16 * 34);
    int m0 = (blockIdx.x / 12) * 32;
    int n0 = (blockIdx.x % 12) * 64;
    int tr = tid >> 4, tc = tid & 15;
    float acc[2][4] = {};
    int bkr = tid >> 4, bcq = (tid & 15) * 4;

    for (int k0 = 0; k0 < K; k0 += 16) {
        if (tid < 128) {
            int r = tid >> 2, kq = (tid & 3) * 4;
            float4 av = *(const float4*)(A + (size_t)(m0 + r) * K + k0 + kq);
            As[kq + 0][r] = av.x;
            As[kq + 1][r] = av.y;
            As[kq + 2][r] = av.z;
            As[kq + 3][r] = av.w;
        }
        float4 bv = *(const float4*)(Bw + (size_t)(k0 + bkr) * N + n0 + bcq);
        *(float4*)&Bs[bkr][bcq] = bv;
        __syncthreads();
#pragma unroll
        for (int kk = 0; kk < 16; ++kk) {
            float2 a2 = *(float2*)&As[kk][tr * 2];
            float4 b4 = *(float4*)&Bs[kk][tc * 4];
            acc[0][0] = fmaf(a2.x, b4.x, acc[0][0]);
            acc[0][1] = fmaf(a2.x, b4.y, acc[0][1]);
            acc[0][2] = fmaf(a2.x, b4.z, acc[0][2]);
            acc[0][3] = fmaf(a2.x, b4.w, acc[0][3]);
            acc[1][0] = fmaf(a2.y, b4.x, acc[1][0]);
            acc[1][1] = fmaf(a2.y, b4.y, acc[1][1]);
            acc[1][2] = fmaf(a2.y, b4.z, acc[1][2]);
            acc[1][3] = fmaf(a2.y, b4.w, acc[1][3]);
        }
        __syncthreads();
    }
    int sec = n0 >> 8;
    float* dst = (sec == 0) ? qT : (sec == 1) ? kT : vT;
    int cc0 = (n0 & 255) + tc * 4;
    int h = cc0 >> 5;
    int e0 = cc0 & 31;
#pragma unroll
    for (int i = 0; i < 2; ++i) {
        int m = m0 + tr * 2 + i;
        int bq = m >> 9, t = m & (Tdim - 1);
        float4 val = make_float4(acc[i][0], acc[i][1], acc[i][2], acc[i][3]);
        *(float4*)&dst[(((size_t)bq * Hdim + h) * Tdim + t) * Edim + e0] = val;
    }
}

// ---------------------------------------------------------------------------
// Kernel 2: attention, single-pass ONLINE softmax (flash-style).
// grid = (32 tile-pairs, 16 bh), block = 512 (8 waves). LDS ~48 KB.
// __launch_bounds__(512) with NO min-waves arg: R7 proved (512,6)->40 VGPR
// catastrophic spill; R8 proved (512,4) makes the allocator target the
// 64-VGPR occupancy step with ~21 MB scratch (k4[8]+acc[8] simultaneously
// live in the fused loop). R2 precedent: bare (512) lands ~92-128 VGPR,
// spill-free. Expect 2 blocks/CU via LDS, zero scratch.
// ---------------------------------------------------------------------------
__global__ __launch_bounds__(512) void attn_kernel(
    const float* __restrict__ qT, const float* __restrict__ kT,
    const float* __restrict__ vT, const int* __restrict__ bm,
    const float* __restrict__ ekt, const float* __restrict__ evt,
    const float* __restrict__ abt, float* __restrict__ y)
{
    __shared__ float kv[JT][36];                 // k then v tile
    __shared__ float qm[TI][NTYPES][36];         // q*ekt; overlaid by spart
    __shared__ float ssp[TI][132];               // tile scores -> probs
    __shared__ unsigned int st1pt[JT];           // nibbles bm[b,j,i0+ii], tile
    __shared__ unsigned int st2pt[JT];           // nibbles bm[b,i0+ii,j], tile
    __shared__ float sekt[NTYPES][36];
    __shared__ float sevt[NTYPES][36];
    __shared__ float sq[TI][36];
    __shared__ float sabt[NTYPES];
    __shared__ float sm[TI], sl[TI], salpha[TI];

    float* spart = (float*)qm;                   // overlay: [8][TI][Edim]

    const int pairIdx = blockIdx.x;   // 0..31
    const int bh = blockIdx.y;        // 0..15
    const int h = bh & (Hdim - 1);
    const int b = bh >> 3;
    const int tid = threadIdx.x;
    const int wave = tid >> 6;
    const int lane = tid & 63;
    const float inv_scale = 0.17677669529663687f;  // 1/sqrt(32)

    const float* qbase = qT + (size_t)bh * Tdim * Edim;
    const float* kbase = kT + (size_t)bh * Tdim * Edim;
    const float* vbase = vT + (size_t)bh * Tdim * Edim;
    const int* bmb = bm + (size_t)b * Tdim * Tdim;

    if (tid < 128) {
        int t = tid >> 3, eq = tid & 7;
        *(float4*)&sekt[t][eq * 4] = *(const float4*)&ekt[t * Cdim + h * Edim + eq * 4];
        *(float4*)&sevt[t][eq * 4] = *(const float4*)&evt[t * Cdim + h * Edim + eq * 4];
    }
    if (tid < NTYPES) sabt[tid] = abt[tid * Hdim + h];

    for (int rep = 0; rep < 2; ++rep) {
        int tau = rep ? (63 - pairIdx) : pairIdx;
        int i0 = tau * TI;
        int imax = i0 + TI - 1;
        int njt = (imax >> 7) + 1;

        __syncthreads();  // prev rep epilogue reads done / tables ready

        // stage q rows; init online-softmax state
        if (tid < TI * 8) {
            int r = tid >> 3, eq = tid & 7;
            *(float4*)&sq[r][eq * 4] =
                *(const float4*)&qbase[(size_t)(i0 + r) * Edim + eq * 4];
        }
        if (tid < TI) { sm[tid] = -1e30f; sl[tid] = 0.f; }
        __syncthreads();
        // build qm[ii][t][e] = q[i0+ii][e] * ekt[t][e]
        for (int idx = tid; idx < TI * NTYPES * 8; idx += 512) {
            int eq = idx & 7;
            int t = (idx >> 3) & (NTYPES - 1);
            int r = idx >> 7;
            float4 qv = *(float4*)&sq[r][eq * 4];
            float4 ev = *(float4*)&sekt[t][eq * 4];
            float4 o;
            o.x = qv.x * ev.x; o.y = qv.y * ev.y;
            o.z = qv.z * ev.z; o.w = qv.w * ev.w;
            *(float4*)&qm[r][t][eq * 4] = o;
        }

        float4 acc[TI];
#pragma unroll
        for (int ii = 0; ii < TI; ++ii) acc[ii] = make_float4(0.f, 0.f, 0.f, 0.f);
        int gid = tid >> 3;        // 64 groups of 8 (PV layout)
        int eqg = tid & 7;

        for (int jt = 0; jt < njt; ++jt) {
            int j0 = jt << 7;
            __syncthreads();   // A: qm ready (jt=0) / prev PV done
            // stage k-tile + both nibble tables
            {
                int r0 = tid >> 3, eq0 = tid & 7;
                *(float4*)&kv[r0][eq0 * 4] =
                    *(const float4*)&kbase[(size_t)(j0 + r0) * Edim + eq0 * 4];
                int idx1 = tid + 512;
                int r1 = idx1 >> 3, eq1 = idx1 & 7;
                *(float4*)&kv[r1][eq1 * 4] =
                    *(const float4*)&kbase[(size_t)(j0 + r1) * Edim + eq1 * 4];
            }
            if (tid < JT) {
                const int* rowp = bmb + (size_t)(j0 + tid) * Tdim + i0;
                int4 lo = *(const int4*)rowp;
                int4 hi = *(const int4*)(rowp + 4);
                st1pt[tid] =
                    ((unsigned)(lo.x & 15)) | (((unsigned)(lo.y & 15)) << 4) |
                    (((unsigned)(lo.z & 15)) << 8) | (((unsigned)(lo.w & 15)) << 12) |
                    (((unsigned)(hi.x & 15)) << 16) | (((unsigned)(hi.y & 15)) << 20) |
                    (((unsigned)(hi.z & 15)) << 24) | (((unsigned)(hi.w & 15)) << 28);
                unsigned w2 = 0;
#pragma unroll
                for (int iiq = 0; iiq < 8; ++iiq)
                    w2 |= ((unsigned)(bmb[(size_t)(i0 + iiq) * Tdim + j0 + tid] & 15))
                          << (iiq * 4);
                st2pt[tid] = w2;
            }
            __syncthreads();   // B: k + tables ready

            // ---- score phase: lane owns j ----
            {
                int jsub = wave & 1;
                int jl = (jsub << 6) + lane;
                int j = j0 + jl;
                float4 k4[8];
#pragma unroll
                for (int eq = 0; eq < 8; ++eq) k4[eq] = *(float4*)&kv[jl][eq * 4];
                unsigned tp = st1pt[jl];
                unsigned tp2 = st2pt[jl];
#pragma unroll
                for (int u = 0; u < 2; ++u) {
                    int ii = (wave >> 1) + (u << 2);
                    int i = i0 + ii;
                    if (j0 + (jsub << 6) > i) continue;   // wave-uniform skip
                    int t1 = (tp >> (ii * 4)) & 15;
                    int t2 = (tp2 >> (ii * 4)) & 15;
                    float s = 0.f;
#pragma unroll
                    for (int eq = 0; eq < 8; ++eq) {
                        float4 qv = *(float4*)&qm[ii][t1][eq * 4];
                        s = fmaf(qv.x, k4[eq].x, s);
                        s = fmaf(qv.y, k4[eq].y, s);
                        s = fmaf(qv.z, k4[eq].z, s);
                        s = fmaf(qv.w, k4[eq].w, s);
                    }
                    if (j <= i) ssp[ii][jl] = s * inv_scale + sabt[t2];
                }
            }
            __syncthreads();   // C: tile scores visible; kv (k) dead

            // ---- stage v-tile (overlaps softmax) ----
            {
                int r0 = tid >> 3, eq0 = tid & 7;
                *(float4*)&kv[r0][eq0 * 4] =
                    *(const float4*)&vbase[(size_t)(j0 + r0) * Edim + eq0 * 4];
                int idx1 = tid + 512;
                int r1 = idx1 >> 3, eq1 = idx1 & 7;
                *(float4*)&kv[r1][eq1 * 4] =
                    *(const float4*)&vbase[(size_t)(j0 + r1) * Edim + eq1 * 4];
            }
            // ---- online softmax update: wave ii owns row i ----
            {
                int ii = wave;
                int i = i0 + ii;
                float s0 = (j0 + lane <= i) ? ssp[ii][lane] : -1e30f;
                float s1 = (j0 + 64 + lane <= i) ? ssp[ii][64 + lane] : -1e30f;
                float mx = fmaxf(s0, s1);
                for (int off = 32; off; off >>= 1) mx = fmaxf(mx, __shfl_xor(mx, off));
                float m_old = sm[ii];
                float m_new = fmaxf(m_old, mx);
                float p0 = __expf(s0 - m_new);
                float p1 = __expf(s1 - m_new);
                ssp[ii][lane] = p0;
                ssp[ii][64 + lane] = p1;
                float sum = p0 + p1;
                for (int off = 32; off; off >>= 1) sum += __shfl_xor(sum, off);
                if (lane == 0) {
                    salpha[ii] = __expf(m_old - m_new);
                    sm[ii] = m_new;
                    sl[ii] = sl[ii] * salpha[ii] + sum;
                }
            }
            __syncthreads();   // D: v, p, alpha, l ready

            // ---- PV phase: rescale then accumulate ----
#pragma unroll
            for (int ii = 0; ii < TI; ++ii) {
                float a = salpha[ii];
                acc[ii].x *= a; acc[ii].y *= a; acc[ii].z *= a; acc[ii].w *= a;
            }
#pragma unroll
            for (int sub = 0; sub < 2; ++sub) {
                int jl = (sub << 6) + gid;
                float4 v4 = *(float4*)&kv[jl][eqg * 4];
                unsigned tp = st1pt[jl];
#pragma unroll
                for (int ii = 0; ii < TI; ++ii) {
                    int i = i0 + ii;
                    if (j0 + (sub << 6) > i) continue;  // block-uniform skip
                    float p = ssp[ii][jl];              // 0 for masked j
                    int t1 = (tp >> (ii * 4)) & 15;
                    float4 ev = *(float4*)&sevt[t1][eqg * 4];
                    acc[ii].x = fmaf(p * ev.x, v4.x, acc[ii].x);
                    acc[ii].y = fmaf(p * ev.y, v4.y, acc[ii].y);
                    acc[ii].z = fmaf(p * ev.z, v4.z, acc[ii].z);
                    acc[ii].w = fmaf(p * ev.w, v4.w, acc[ii].w);
                }
            }
        }
        // reduce across the wave's 8 groups (lane bits 3,4,5)
#pragma unroll
        for (int ii = 0; ii < TI; ++ii) {
#pragma unroll
            for (int m = 8; m <= 32; m <<= 1) {
                acc[ii].x += __shfl_xor(acc[ii].x, m);
                acc[ii].y += __shfl_xor(acc[ii].y, m);
                acc[ii].z += __shfl_xor(acc[ii].z, m);
                acc[ii].w += __shfl_xor(acc[ii].w, m);
            }
        }
        __syncthreads();   // all waves past last score phase; qm free for spart
        if (lane < 8) {
#pragma unroll
            for (int ii = 0; ii < TI; ++ii)
                *(float4*)&spart[((wave * TI + ii) << 5) + lane * 4] = acc[ii];
        }
        __syncthreads();
        if (tid < TI * Edim) {
            int ii = tid >> 5, e = tid & 31;
            float yv = 0.f;
#pragma unroll
            for (int w = 0; w < 8; ++w) yv += spart[((w * TI + ii) << 5) + e];
            yv /= sl[ii];
            y[((size_t)(b * Tdim + i0 + ii)) * Cdim + h * Edim + e] = yv;
        }
    }
}

// ---------------------------------------------------------------------------
// Kernel 3: proj GEMM (M=1024, K=256, N=256) -> d_out (B,T,C), 32x64 tiles
// ---------------------------------------------------------------------------
__global__ __launch_bounds__(256) void proj_gemm_kernel(
    const float* __restrict__ A, const float* __restrict__ Bw,
    float* __restrict__ out)
{
    const int N = Cdim;
    const int K = Cdim;
    __shared__ float As[16][34];
    __shared__ float Bs[16][64];
    int m0 = blockIdx.y * 32;
    int n0 = blockIdx.x * 64;
    int tid = threadIdx.x;
    int tr = tid >> 4, tc = tid & 15;
    float acc[2][4] = {};
    int bkr = tid >> 4, bcq = (tid & 15) * 4;

    for (int k0 = 0; k0 < K; k0 += 16) {
        if (tid < 128) {
            int r = tid >> 2, kq = (tid & 3) * 4;
            float4 av = *(const float4*)(A + (size_t)(m0 + r) * K + k0 + kq);
            As[kq + 0][r] = av.x;
            As[kq + 1][r] = av.y;
            As[kq + 2][r] = av.z;
            As[kq + 3][r] = av.w;
        }
        float4 bv = *(const float4*)(Bw + (size_t)(k0 + bkr) * N + n0 + bcq);
        *(float4*)&Bs[bkr][bcq] = bv;
        __syncthreads();
#pragma unroll
        for (int kk = 0; kk < 16; ++kk) {
            float2 a2 = *(float2*)&As[kk][tr * 2];
            float4 b4 = *(float4*)&Bs[kk][tc * 4];
            acc[0][0] = fmaf(a2.x, b4.x, acc[0][0]);
            acc[0][1] = fmaf(a2.x, b4.y, acc[0][1]);
            acc[0][2] = fmaf(a2.x, b4.z, acc[0][2]);
            acc[0][3] = fmaf(a2.x, b4.w, acc[0][3]);
            acc[1][0] = fmaf(a2.y, b4.x, acc[1][0]);
            acc[1][1] = fmaf(a2.y, b4.y, acc[1][1]);
            acc[1][2] = fmaf(a2.y, b4.z, acc[1][2]);
            acc[1][3] = fmaf(a2.y, b4.w, acc[1][3]);
        }
        __syncthreads();
    }
#pragma unroll
    for (int i = 0; i < 2; ++i) {
        int m = m0 + tr * 2 + i;
        float4 val = make_float4(acc[i][0], acc[i][1], acc[i][2], acc[i][3]);
        *(float4*)&out[(size_t)m * N + n0 + tc * 4] = val;
    }
}

// ---------------------------------------------------------------------------
extern "C" void kernel_launch(void* const* d_in, const int* in_sizes, int n_in,
                              void* d_out, int out_size, void* d_ws, size_t ws_size,
                              hipStream_t stream) {
    (void)in_sizes; (void)n_in; (void)out_size; (void)ws_size;
    const float* x = (const float*)d_in[0];
    const int* bias_matrix = (const int*)d_in[1];
    const float* w_attn = (const float*)d_in[2];
    const float* w_proj = (const float*)d_in[3];
    const float* w_edge_k = (const float*)d_in[4];
    const float* w_edge_v = (const float*)d_in[5];
    const float* edge_emb = (const float*)d_in[6];
    const float* attn_bias = (const float*)d_in[7];
    float* out = (float*)d_out;

    const size_t n_qkv = (size_t)Bdim * Hdim * Tdim * Edim;
    float* ws = (float*)d_ws;
    float* qT = ws;
    float* kT = qT + n_qkv;
    float* vT = kT + n_qkv;
    float* y = vT + n_qkv;
    float* ekt = y + (size_t)Bdim * Tdim * Cdim;
    float* evt = ekt + (size_t)NTYPES * Cdim;

    pre_kernel<<<400, 256, 0, stream>>>(x, w_attn, edge_emb, w_edge_k, w_edge_v,
                                        qT, kT, vT, ekt, evt);
    attn_kernel<<<dim3(32, 16), 512, 0, stream>>>(qT, kT, vT, bias_matrix,
                                                  ekt, evt, attn_bias, y);
    proj_gemm_kernel<<<dim3(4, 32), 256, 0, stream>>>(y, w_proj, out);
}

// Round 10
// 136.046 us; speedup vs baseline: 1.0751x; 1.0751x over previous
//
#include <hip/hip_runtime.h>
#include <hip/hip_bf16.h>
#include <math.h>

// Problem constants
#define Bdim 2
#define Tdim 512
#define Cdim 256
#define Hdim 8
#define Edim 32
#define NTYPES 16
#define TI 8       // i-tile size
#define JT 128     // j-tile size

// ---------------------------------------------------------------------------
// Kernel 1: fused edge-tables + qkv GEMM.
// blocks 0..383: qkv GEMM (M=1024,K=256,N=768), 32x64 tile, scatter (B,H,T,E)
// blocks 384..399: ekt/evt = emb[t] @ w_edge_{k,v}
// ---------------------------------------------------------------------------
__global__ __launch_bounds__(256) void pre_kernel(
    const float* __restrict__ A, const float* __restrict__ Bw,
    const float* __restrict__ emb, const float* __restrict__ wk,
    const float* __restrict__ wv,
    float* __restrict__ qT, float* __restrict__ kT, float* __restrict__ vT,
    float* __restrict__ ekt, float* __restrict__ evt)
{
    __shared__ float smem[16 * 34 + 16 * 64];
    int tid = threadIdx.x;

    if (blockIdx.x >= 384) {
        int t = blockIdx.x - 384;
        float* se = smem;
        se[tid] = emb[t * Cdim + tid];
        __syncthreads();
        float a = 0.f, b = 0.f;
        for (int k = 0; k < Cdim; ++k) {
            float ev = se[k];
            a = fmaf(ev, wk[k * Cdim + tid], a);
            b = fmaf(ev, wv[k * Cdim + tid], b);
        }
        ekt[t * Cdim + tid] = a;
        evt[t * Cdim + tid] = b;
        return;
    }

    const int N = 3 * Cdim;
    const int K = Cdim;
    float (*As)[34] = (float(*)[34])smem;
    float (*Bs)[64] = (float(*)[64])(smem + 16 * 34);
    int m0 = (blockIdx.x / 12) * 32;
    int n0 = (blockIdx.x % 12) * 64;
    int tr = tid >> 4, tc = tid & 15;
    float acc[2][4] = {};
    int bkr = tid >> 4, bcq = (tid & 15) * 4;

    for (int k0 = 0; k0 < K; k0 += 16) {
        if (tid < 128) {
            int r = tid >> 2, kq = (tid & 3) * 4;
            float4 av = *(const float4*)(A + (size_t)(m0 + r) * K + k0 + kq);
            As[kq + 0][r] = av.x;
            As[kq + 1][r] = av.y;
            As[kq + 2][r] = av.z;
            As[kq + 3][r] = av.w;
        }
        float4 bv = *(const float4*)(Bw + (size_t)(k0 + bkr) * N + n0 + bcq);
        *(float4*)&Bs[bkr][bcq] = bv;
        __syncthreads();
#pragma unroll
        for (int kk = 0; kk < 16; ++kk) {
            float2 a2 = *(float2*)&As[kk][tr * 2];
            float4 b4 = *(float4*)&Bs[kk][tc * 4];
            acc[0][0] = fmaf(a2.x, b4.x, acc[0][0]);
            acc[0][1] = fmaf(a2.x, b4.y, acc[0][1]);
            acc[0][2] = fmaf(a2.x, b4.z, acc[0][2]);
            acc[0][3] = fmaf(a2.x, b4.w, acc[0][3]);
            acc[1][0] = fmaf(a2.y, b4.x, acc[1][0]);
            acc[1][1] = fmaf(a2.y, b4.y, acc[1][1]);
            acc[1][2] = fmaf(a2.y, b4.z, acc[1][2]);
            acc[1][3] = fmaf(a2.y, b4.w, acc[1][3]);
        }
        __syncthreads();
    }
    int sec = n0 >> 8;
    float* dst = (sec == 0) ? qT : (sec == 1) ? kT : vT;
    int cc0 = (n0 & 255) + tc * 4;
    int h = cc0 >> 5;
    int e0 = cc0 & 31;
#pragma unroll
    for (int i = 0; i < 2; ++i) {
        int m = m0 + tr * 2 + i;
        int bq = m >> 9, t = m & (Tdim - 1);
        float4 val = make_float4(acc[i][0], acc[i][1], acc[i][2], acc[i][3]);
        *(float4*)&dst[(((size_t)bq * Hdim + h) * Tdim + t) * Edim + e0] = val;
    }
}

// ---------------------------------------------------------------------------
// Kernel 2: attention, two-pass (R6 structure, best known) with qm removed.
// grid = (32 tile-pairs, 16 bh), block = 512 (8 waves).
// Score phase reads sq[ii] (wave-broadcast, free) and sekt[t1] (2-way
// aliased gather, free) directly: s += (q*ekt)*k. This deletes the 18.4 KB
// qm buffer + its build step -> LDS ~45 KB (3 blocks/CU) and keeps pass-A
// live registers at k4(32)+~20, pass-B at acc(32)+~15 -> natural pressure
// ~55, so (512,4) should land on the 64-VGPR occupancy step spill-free
// (R9 proved 65+ VGPR = 4 waves/SIMD cliff; R8 proved spills cost ~20 us).
// spart epilogue overlays ss (dead after pass B).
// ---------------------------------------------------------------------------
__global__ __launch_bounds__(512, 4) void attn_kernel(
    const float* __restrict__ qT, const float* __restrict__ kT,
    const float* __restrict__ vT, const int* __restrict__ bm,
    const float* __restrict__ ekt, const float* __restrict__ evt,
    const float* __restrict__ abt, float* __restrict__ y)
{
    __shared__ float kv[JT][36];                 // k or v tile
    __shared__ float ss[TI][516];                // scores -> probs; epilogue spart
    __shared__ unsigned int st1pf[Tdim];         // nibbles bm[b,j,i0+ii], whole rep
    __shared__ unsigned int st2pf[Tdim];         // nibbles bm[b,i0+ii,j], whole rep
    __shared__ float sekt[NTYPES][36];
    __shared__ float sevt[NTYPES][36];
    __shared__ float sq[TI][36];
    __shared__ float sabt[NTYPES];
    __shared__ float sinv[TI];

    float* spart = (float*)ss;                   // overlay: [8][TI][Edim]

    const int pairIdx = blockIdx.x;   // 0..31
    const int bh = blockIdx.y;        // 0..15
    const int h = bh & (Hdim - 1);
    const int b = bh >> 3;
    const int tid = threadIdx.x;
    const int wave = tid >> 6;
    const int lane = tid & 63;
    const float inv_scale = 0.17677669529663687f;  // 1/sqrt(32)

    const float* qbase = qT + (size_t)bh * Tdim * Edim;
    const float* kbase = kT + (size_t)bh * Tdim * Edim;
    const float* vbase = vT + (size_t)bh * Tdim * Edim;
    const int* bmb = bm + (size_t)b * Tdim * Tdim;

    if (tid < 128) {
        int t = tid >> 3, eq = tid & 7;
        *(float4*)&sekt[t][eq * 4] = *(const float4*)&ekt[t * Cdim + h * Edim + eq * 4];
        *(float4*)&sevt[t][eq * 4] = *(const float4*)&evt[t * Cdim + h * Edim + eq * 4];
    }
    if (tid < NTYPES) sabt[tid] = abt[tid * Hdim + h];

    for (int rep = 0; rep < 2; ++rep) {
        int tau = rep ? (63 - pairIdx) : pairIdx;
        int i0 = tau * TI;
        int imax = i0 + TI - 1;
        int njt = (imax >> 7) + 1;
        int jmax = njt << 7;

        __syncthreads();  // prev rep epilogue (spart reads) done / tables ready

        // stage q rows
        if (tid < TI * 8) {
            int r = tid >> 3, eq = tid & 7;
            *(float4*)&sq[r][eq * 4] =
                *(const float4*)&qbase[(size_t)(i0 + r) * Edim + eq * 4];
        }
        // stage both nibble tables for the whole rep
        if (tid < jmax) {
            const int* rowp = bmb + (size_t)tid * Tdim + i0;
            int4 lo = *(const int4*)rowp;
            int4 hi = *(const int4*)(rowp + 4);
            st1pf[tid] =
                ((unsigned)(lo.x & 15)) | (((unsigned)(lo.y & 15)) << 4) |
                (((unsigned)(lo.z & 15)) << 8) | (((unsigned)(lo.w & 15)) << 12) |
                (((unsigned)(hi.x & 15)) << 16) | (((unsigned)(hi.y & 15)) << 20) |
                (((unsigned)(hi.z & 15)) << 24) | (((unsigned)(hi.w & 15)) << 28);
            unsigned w2 = 0;
#pragma unroll
            for (int iiq = 0; iiq < 8; ++iiq)
                w2 |= ((unsigned)(bmb[(size_t)(i0 + iiq) * Tdim + tid] & 15)) << (iiq * 4);
            st2pf[tid] = w2;
        }
        // prestage k-tile 0
        {
            int r0 = tid >> 3, eq0 = tid & 7;
            *(float4*)&kv[r0][eq0 * 4] =
                *(const float4*)&kbase[(size_t)r0 * Edim + eq0 * 4];
            int idx1 = tid + 512;
            int r1 = idx1 >> 3, eq1 = idx1 & 7;
            *(float4*)&kv[r1][eq1 * 4] =
                *(const float4*)&kbase[(size_t)r1 * Edim + eq1 * 4];
        }

        // ---------------- Pass A: scores ----------------
        for (int jt = 0; jt < njt; ++jt) {
            int j0 = jt << 7;
            if (jt > 0) {
                __syncthreads();   // prev tile consumed
                for (int idx = tid; idx < JT * 8; idx += 512) {
                    int r = idx >> 3, eq = idx & 7;
                    *(float4*)&kv[r][eq * 4] =
                        *(const float4*)&kbase[(size_t)(j0 + r) * Edim + eq * 4];
                }
            }
            __syncthreads();       // jt=0: staging above done; jt>0: staged

            int jsub = wave & 1;
            int jl = (jsub << 6) + lane;
            int j = j0 + jl;
            float4 k4[8];
#pragma unroll
            for (int eq = 0; eq < 8; ++eq) k4[eq] = *(float4*)&kv[jl][eq * 4];
            unsigned tp = st1pf[j];
            unsigned tp2 = st2pf[j];

#pragma unroll
            for (int u = 0; u < 2; ++u) {
                int ii = (wave >> 1) + (u << 2);
                int i = i0 + ii;
                if (j0 + (jsub << 6) > i) continue;   // wave-uniform skip
                int t1 = (tp >> (ii * 4)) & 15;
                int t2 = (tp2 >> (ii * 4)) & 15;
                float s = 0.f;
#pragma unroll
                for (int eq = 0; eq < 8; ++eq) {
                    float4 qv = *(float4*)&sq[ii][eq * 4];      // broadcast
                    float4 ev = *(float4*)&sekt[t1][eq * 4];    // 2-way gather
                    s = fmaf(qv.x * ev.x, k4[eq].x, s);
                    s = fmaf(qv.y * ev.y, k4[eq].y, s);
                    s = fmaf(qv.z * ev.z, k4[eq].z, s);
                    s = fmaf(qv.w * ev.w, k4[eq].w, s);
                }
                if (j <= i) ss[ii][j] = s * inv_scale + sabt[t2];
            }
        }
        __syncthreads();   // all scores written; all pass-A kv reads done

        // prestage v-tile 0 (overlaps softmax)
        {
            int r0 = tid >> 3, eq0 = tid & 7;
            *(float4*)&kv[r0][eq0 * 4] =
                *(const float4*)&vbase[(size_t)r0 * Edim + eq0 * 4];
            int idx1 = tid + 512;
            int r1 = idx1 >> 3, eq1 = idx1 & 7;
            *(float4*)&kv[r1][eq1 * 4] =
                *(const float4*)&vbase[(size_t)r1 * Edim + eq1 * 4];
        }
        // ---------------- softmax (normalization deferred) ----------------
        {
            int ii = wave;
            int i = i0 + ii;
            float m = -1e30f;
            for (int j = lane; j <= i; j += 64) m = fmaxf(m, ss[ii][j]);
            for (int off = 32; off; off >>= 1) m = fmaxf(m, __shfl_xor(m, off));
            float sum = 0.f;
            for (int j = lane; j <= i; j += 64) {
                float p = __expf(ss[ii][j] - m);
                ss[ii][j] = p;
                sum += p;
            }
            for (int off = 32; off; off >>= 1) sum += __shfl_xor(sum, off);
            if (lane == 0) sinv[ii] = 1.0f / sum;
        }

        // ---------------- Pass B: PV ----------------
        float4 acc[TI];
#pragma unroll
        for (int ii = 0; ii < TI; ++ii) acc[ii] = make_float4(0.f, 0.f, 0.f, 0.f);
        int gid = tid >> 3;        // 64 groups of 8
        int eqg = tid & 7;
        for (int jt = 0; jt < njt; ++jt) {
            int j0 = jt << 7;
            if (jt > 0) {
                __syncthreads();   // prev v-tile consumed
                for (int idx = tid; idx < JT * 8; idx += 512) {
                    int r = idx >> 3, eq = idx & 7;
                    *(float4*)&kv[r][eq * 4] =
                        *(const float4*)&vbase[(size_t)(j0 + r) * Edim + eq * 4];
                }
            }
            __syncthreads();       // jt=0: v0 + softmax visible; jt>0: staged
#pragma unroll
            for (int sub = 0; sub < 2; ++sub) {
                int jl = (sub << 6) + gid;
                int j = j0 + jl;
                float4 v4 = *(float4*)&kv[jl][eqg * 4];
                unsigned tp = st1pf[j];
#pragma unroll
                for (int ii = 0; ii < TI; ++ii) {
                    int i = i0 + ii;
                    if (j0 + (sub << 6) > i) continue;  // block-uniform skip
                    float p = (j <= i) ? ss[ii][j] : 0.f;
                    int t1 = (tp >> (ii * 4)) & 15;
                    float4 ev = *(float4*)&sevt[t1][eqg * 4];
                    acc[ii].x = fmaf(p * ev.x, v4.x, acc[ii].x);
                    acc[ii].y = fmaf(p * ev.y, v4.y, acc[ii].y);
                    acc[ii].z = fmaf(p * ev.z, v4.z, acc[ii].z);
                    acc[ii].w = fmaf(p * ev.w, v4.w, acc[ii].w);
                }
            }
        }
        // reduce across the wave's 8 groups (lane bits 3,4,5)
#pragma unroll
        for (int ii = 0; ii < TI; ++ii) {
#pragma unroll
            for (int m = 8; m <= 32; m <<= 1) {
                acc[ii].x += __shfl_xor(acc[ii].x, m);
                acc[ii].y += __shfl_xor(acc[ii].y, m);
                acc[ii].z += __shfl_xor(acc[ii].z, m);
                acc[ii].w += __shfl_xor(acc[ii].w, m);
            }
        }
        __syncthreads();   // all ss reads done; ss free for spart overlay
        if (lane < 8) {
#pragma unroll
            for (int ii = 0; ii < TI; ++ii)
                *(float4*)&spart[((wave * TI + ii) << 5) + lane * 4] = acc[ii];
        }
        __syncthreads();
        if (tid < TI * Edim) {
            int ii = tid >> 5, e = tid & 31;
            float yv = 0.f;
#pragma unroll
            for (int w = 0; w < 8; ++w) yv += spart[((w * TI + ii) << 5) + e];
            yv *= sinv[ii];
            y[((size_t)(b * Tdim + i0 + ii)) * Cdim + h * Edim + e] = yv;
        }
    }
}

// ---------------------------------------------------------------------------
// Kernel 3: proj GEMM (M=1024, K=256, N=256) -> d_out (B,T,C), 32x64 tiles
// ---------------------------------------------------------------------------
__global__ __launch_bounds__(256) void proj_gemm_kernel(
    const float* __restrict__ A, const float* __restrict__ Bw,
    float* __restrict__ out)
{
    const int N = Cdim;
    const int K = Cdim;
    __shared__ float As[16][34];
    __shared__ float Bs[16][64];
    int m0 = blockIdx.y * 32;
    int n0 = blockIdx.x * 64;
    int tid = threadIdx.x;
    int tr = tid >> 4, tc = tid & 15;
    float acc[2][4] = {};
    int bkr = tid >> 4, bcq = (tid & 15) * 4;

    for (int k0 = 0; k0 < K; k0 += 16) {
        if (tid < 128) {
            int r = tid >> 2, kq = (tid & 3) * 4;
            float4 av = *(const float4*)(A + (size_t)(m0 + r) * K + k0 + kq);
            As[kq + 0][r] = av.x;
            As[kq + 1][r] = av.y;
            As[kq + 2][r] = av.z;
            As[kq + 3][r] = av.w;
        }
        float4 bv = *(const float4*)(Bw + (size_t)(k0 + bkr) * N + n0 + bcq);
        *(float4*)&Bs[bkr][bcq] = bv;
        __syncthreads();
#pragma unroll
        for (int kk = 0; kk < 16; ++kk) {
            float2 a2 = *(float2*)&As[kk][tr * 2];
            float4 b4 = *(float4*)&Bs[kk][tc * 4];
            acc[0][0] = fmaf(a2.x, b4.x, acc[0][0]);
            acc[0][1] = fmaf(a2.x, b4.y, acc[0][1]);
            acc[0][2] = fmaf(a2.x, b4.z, acc[0][2]);
            acc[0][3] = fmaf(a2.x, b4.w, acc[0][3]);
            acc[1][0] = fmaf(a2.y, b4.x, acc[1][0]);
            acc[1][1] = fmaf(a2.y, b4.y, acc[1][1]);
            acc[1][2] = fmaf(a2.y, b4.z, acc[1][2]);
            acc[1][3] = fmaf(a2.y, b4.w, acc[1][3]);
        }
        __syncthreads();
    }
#pragma unroll
    for (int i = 0; i < 2; ++i) {
        int m = m0 + tr * 2 + i;
        float4 val = make_float4(acc[i][0], acc[i][1], acc[i][2], acc[i][3]);
        *(float4*)&out[(size_t)m * N + n0 + tc * 4] = val;
    }
}

// ---------------------------------------------------------------------------
extern "C" void kernel_launch(void* const* d_in, const int* in_sizes, int n_in,
                              void* d_out, int out_size, void* d_ws, size_t ws_size,
                              hipStream_t stream) {
    (void)in_sizes; (void)n_in; (void)out_size; (void)ws_size;
    const float* x = (const float*)d_in[0];
    const int* bias_matrix = (const int*)d_in[1];
    const float* w_attn = (const float*)d_in[2];
    const float* w_proj = (const float*)d_in[3];
    const float* w_edge_k = (const float*)d_in[4];
    const float* w_edge_v = (const float*)d_in[5];
    const float* edge_emb = (const float*)d_in[6];
    const float* attn_bias = (const float*)d_in[7];
    float* out = (float*)d_out;

    const size_t n_qkv = (size_t)Bdim * Hdim * Tdim * Edim;
    float* ws = (float*)d_ws;
    float* qT = ws;
    float* kT = qT + n_qkv;
    float* vT = kT + n_qkv;
    float* y = vT + n_qkv;
    float* ekt = y + (size_t)Bdim * Tdim * Cdim;
    float* evt = ekt + (size_t)NTYPES * Cdim;

    pre_kernel<<<400, 256, 0, stream>>>(x, w_attn, edge_emb, w_edge_k, w_edge_v,
                                        qT, kT, vT, ekt, evt);
    attn_kernel<<<dim3(32, 16), 512, 0, stream>>>(qT, kT, vT, bias_matrix,
                                                  ekt, evt, attn_bias, y);
    proj_gemm_kernel<<<dim3(4, 32), 256, 0, stream>>>(y, w_proj, out);
}

// Round 11
// 132.761 us; speedup vs baseline: 1.1017x; 1.0247x over previous
//
#include <hip/hip_runtime.h>
#include <hip/hip_bf16.h>
#include <math.h>

// Problem constants
#define Bdim 2
#define Tdim 512
#define Cdim 256
#define Hdim 8
#define Edim 32
#define NTYPES 16
#define TI 8       // i-tile size
#define JT 128     // j-tile size

// ---------------------------------------------------------------------------
// Kernel 1: fused edge-tables + qkv GEMM.
// blocks 0..383: qkv GEMM (M=1024,K=256,N=768), 32x64 tile, scatter (B,H,T,E)
// blocks 384..399: ekt/evt = emb[t] @ w_edge_{k,v}
// ---------------------------------------------------------------------------
__global__ __launch_bounds__(256) void pre_kernel(
    const float* __restrict__ A, const float* __restrict__ Bw,
    const float* __restrict__ emb, const float* __restrict__ wk,
    const float* __restrict__ wv,
    float* __restrict__ qT, float* __restrict__ kT, float* __restrict__ vT,
    float* __restrict__ ekt, float* __restrict__ evt)
{
    __shared__ float smem[16 * 34 + 16 * 64];
    int tid = threadIdx.x;

    if (blockIdx.x >= 384) {
        // ---- edge tables ----
        int t = blockIdx.x - 384;
        float* se = smem;
        se[tid] = emb[t * Cdim + tid];
        __syncthreads();
        float a = 0.f, b = 0.f;
        for (int k = 0; k < Cdim; ++k) {
            float ev = se[k];
            a = fmaf(ev, wk[k * Cdim + tid], a);
            b = fmaf(ev, wv[k * Cdim + tid], b);
        }
        ekt[t * Cdim + tid] = a;
        evt[t * Cdim + tid] = b;
        return;
    }

    const int N = 3 * Cdim;
    const int K = Cdim;
    float (*As)[34] = (float(*)[34])smem;
    float (*Bs)[64] = (float(*)[64])(smem + 16 * 34);
    int m0 = (blockIdx.x / 12) * 32;
    int n0 = (blockIdx.x % 12) * 64;
    int tr = tid >> 4, tc = tid & 15;
    float acc[2][4] = {};
    int bkr = tid >> 4, bcq = (tid & 15) * 4;

    for (int k0 = 0; k0 < K; k0 += 16) {
        if (tid < 128) {
            int r = tid >> 2, kq = (tid & 3) * 4;
            float4 av = *(const float4*)(A + (size_t)(m0 + r) * K + k0 + kq);
            As[kq + 0][r] = av.x;
            As[kq + 1][r] = av.y;
            As[kq + 2][r] = av.z;
            As[kq + 3][r] = av.w;
        }
        float4 bv = *(const float4*)(Bw + (size_t)(k0 + bkr) * N + n0 + bcq);
        *(float4*)&Bs[bkr][bcq] = bv;
        __syncthreads();
#pragma unroll
        for (int kk = 0; kk < 16; ++kk) {
            float2 a2 = *(float2*)&As[kk][tr * 2];
            float4 b4 = *(float4*)&Bs[kk][tc * 4];
            acc[0][0] = fmaf(a2.x, b4.x, acc[0][0]);
            acc[0][1] = fmaf(a2.x, b4.y, acc[0][1]);
            acc[0][2] = fmaf(a2.x, b4.z, acc[0][2]);
            acc[0][3] = fmaf(a2.x, b4.w, acc[0][3]);
            acc[1][0] = fmaf(a2.y, b4.x, acc[1][0]);
            acc[1][1] = fmaf(a2.y, b4.y, acc[1][1]);
            acc[1][2] = fmaf(a2.y, b4.z, acc[1][2]);
            acc[1][3] = fmaf(a2.y, b4.w, acc[1][3]);
        }
        __syncthreads();
    }
    int sec = n0 >> 8;
    float* dst = (sec == 0) ? qT : (sec == 1) ? kT : vT;
    int cc0 = (n0 & 255) + tc * 4;
    int h = cc0 >> 5;
    int e0 = cc0 & 31;
#pragma unroll
    for (int i = 0; i < 2; ++i) {
        int m = m0 + tr * 2 + i;
        int bq = m >> 9, t = m & (Tdim - 1);
        float4 val = make_float4(acc[i][0], acc[i][1], acc[i][2], acc[i][3]);
        *(float4*)&dst[(((size_t)bq * Hdim + h) * Tdim + t) * Edim + e0] = val;
    }
}

// ---------------------------------------------------------------------------
// Kernel 2: attention (best-measured configuration, Round-6 bench: 133.0 us).
// grid = (32 tile-pairs, 16 bh), block = 512 (8 waves). Two-pass, qm
// premultiplied, st1pf/st2pf full-rep nibble tables (no per-pair global
// loads), k0/v0 prestaged under qm-build/softmax, spart overlays qm.
// LDS ~62 KB -> 2 blocks/CU, (512,4), VGPR ~92, zero spill.
// Do NOT: register-held prefetch (R4: spill), min-waves >4 (R7: 40-VGPR
// catastrophic spill), online softmax (R7-R9: 4 dependent barriers/tile,
// never beat this), qm removal (R10: +32 v_mul/pair, +3 us).
// ---------------------------------------------------------------------------
__global__ __launch_bounds__(512, 4) void attn_kernel(
    const float* __restrict__ qT, const float* __restrict__ kT,
    const float* __restrict__ vT, const int* __restrict__ bm,
    const float* __restrict__ ekt, const float* __restrict__ evt,
    const float* __restrict__ abt, float* __restrict__ y)
{
    __shared__ float kv[JT][36];                 // k or v tile
    __shared__ float qm[TI][NTYPES][36];         // q*ekt; later overlaid by spart
    __shared__ float ss[TI][516];                // scores -> probs
    __shared__ unsigned int st1pf[Tdim];         // nibbles of bm[b,j,i0+ii]
    __shared__ unsigned int st2pf[Tdim];         // nibbles of bm[b,i0+ii,j]
    __shared__ float sekt[NTYPES][36];
    __shared__ float sevt[NTYPES][36];
    __shared__ float sq[TI][36];
    __shared__ float sabt[NTYPES];
    __shared__ float sinv[TI];

    float* spart = (float*)qm;                   // overlay: [8][TI][Edim]

    const int pairIdx = blockIdx.x;   // 0..31
    const int bh = blockIdx.y;        // 0..15
    const int h = bh & (Hdim - 1);
    const int b = bh >> 3;
    const int tid = threadIdx.x;
    const int wave = tid >> 6;
    const int lane = tid & 63;
    const float inv_scale = 0.17677669529663687f;  // 1/sqrt(32)

    const float* qbase = qT + (size_t)bh * Tdim * Edim;
    const float* kbase = kT + (size_t)bh * Tdim * Edim;
    const float* vbase = vT + (size_t)bh * Tdim * Edim;
    const int* bmb = bm + (size_t)b * Tdim * Tdim;

    if (tid < 128) {
        int t = tid >> 3, eq = tid & 7;
        *(float4*)&sekt[t][eq * 4] = *(const float4*)&ekt[t * Cdim + h * Edim + eq * 4];
        *(float4*)&sevt[t][eq * 4] = *(const float4*)&evt[t * Cdim + h * Edim + eq * 4];
    }
    if (tid < NTYPES) sabt[tid] = abt[tid * Hdim + h];

    for (int rep = 0; rep < 2; ++rep) {
        int tau = rep ? (63 - pairIdx) : pairIdx;
        int i0 = tau * TI;
        int imax = i0 + TI - 1;
        int njt = (imax >> 7) + 1;
        int jmax = njt << 7;

        __syncthreads();  // prev rep fully consumed / tables ready

        // stage q rows
        if (tid < TI * 8) {
            int r = tid >> 3, eq = tid & 7;
            *(float4*)&sq[r][eq * 4] =
                *(const float4*)&qbase[(size_t)(i0 + r) * Edim + eq * 4];
        }
        // stage both nibble tables for the whole rep
        if (tid < jmax) {
            // st1pf[j]: bm[b, j, i0..i0+7]  (score/PV modulation types)
            const int* rowp = bmb + (size_t)tid * Tdim + i0;
            int4 lo = *(const int4*)rowp;
            int4 hi = *(const int4*)(rowp + 4);
            st1pf[tid] =
                ((unsigned)(lo.x & 15)) | (((unsigned)(lo.y & 15)) << 4) |
                (((unsigned)(lo.z & 15)) << 8) | (((unsigned)(lo.w & 15)) << 12) |
                (((unsigned)(hi.x & 15)) << 16) | (((unsigned)(hi.y & 15)) << 20) |
                (((unsigned)(hi.z & 15)) << 24) | (((unsigned)(hi.w & 15)) << 28);
            // st2pf[j]: bm[b, i0..i0+7, j]  (attn-bias types, transposed index)
            unsigned w2 = 0;
#pragma unroll
            for (int iiq = 0; iiq < 8; ++iiq)
                w2 |= ((unsigned)(bmb[(size_t)(i0 + iiq) * Tdim + tid] & 15)) << (iiq * 4);
            st2pf[tid] = w2;
        }
        // prestage k-tile 0 (overlaps with qm build below)
        {
            int r0 = tid >> 3, eq0 = tid & 7;
            *(float4*)&kv[r0][eq0 * 4] =
                *(const float4*)&kbase[(size_t)r0 * Edim + eq0 * 4];
            int idx1 = tid + 512;
            int r1 = idx1 >> 3, eq1 = idx1 & 7;
            *(float4*)&kv[r1][eq1 * 4] =
                *(const float4*)&kbase[(size_t)r1 * Edim + eq1 * 4];
        }
        __syncthreads();
        // build qm[ii][t][e] = q[i0+ii][e] * ekt[t][e]
        for (int idx = tid; idx < TI * NTYPES * 8; idx += 512) {
            int eq = idx & 7;
            int t = (idx >> 3) & (NTYPES - 1);
            int r = idx >> 7;
            float4 qv = *(float4*)&sq[r][eq * 4];
            float4 ev = *(float4*)&sekt[t][eq * 4];
            float4 o;
            o.x = qv.x * ev.x; o.y = qv.y * ev.y;
            o.z = qv.z * ev.z; o.w = qv.w * ev.w;
            *(float4*)&qm[r][t][eq * 4] = o;
        }

        // ---------------- Pass A: scores ----------------
        for (int jt = 0; jt < njt; ++jt) {
            int j0 = jt << 7;
            if (jt > 0) {
                __syncthreads();   // prev tile consumed
                for (int idx = tid; idx < JT * 8; idx += 512) {
                    int r = idx >> 3, eq = idx & 7;
                    *(float4*)&kv[r][eq * 4] =
                        *(const float4*)&kbase[(size_t)(j0 + r) * Edim + eq * 4];
                }
            }
            __syncthreads();       // jt=0: qm+k0 ready; jt>0: staged

            int jsub = wave & 1;
            int jl = (jsub << 6) + lane;
            int j = j0 + jl;
            float4 k4[8];
#pragma unroll
            for (int eq = 0; eq < 8; ++eq) k4[eq] = *(float4*)&kv[jl][eq * 4];
            unsigned tp = st1pf[j];
            unsigned tp2 = st2pf[j];

#pragma unroll
            for (int u = 0; u < 2; ++u) {
                int ii = (wave >> 1) + (u << 2);
                int i = i0 + ii;
                if (j0 + (jsub << 6) > i) continue;   // wave-uniform skip
                int t1 = (tp >> (ii * 4)) & 15;
                int t2 = (tp2 >> (ii * 4)) & 15;
                float s = 0.f;
#pragma unroll
                for (int eq = 0; eq < 8; ++eq) {
                    float4 qv = *(float4*)&qm[ii][t1][eq * 4];
                    s = fmaf(qv.x, k4[eq].x, s);
                    s = fmaf(qv.y, k4[eq].y, s);
                    s = fmaf(qv.z, k4[eq].z, s);
                    s = fmaf(qv.w, k4[eq].w, s);
                }
                if (j <= i) ss[ii][j] = s * inv_scale + sabt[t2];
            }
        }
        __syncthreads();   // all scores written; all pass-A kv reads done

        // prestage v-tile 0 (overlaps softmax)
        {
            int r0 = tid >> 3, eq0 = tid & 7;
            *(float4*)&kv[r0][eq0 * 4] =
                *(const float4*)&vbase[(size_t)r0 * Edim + eq0 * 4];
            int idx1 = tid + 512;
            int r1 = idx1 >> 3, eq1 = idx1 & 7;
            *(float4*)&kv[r1][eq1 * 4] =
                *(const float4*)&vbase[(size_t)r1 * Edim + eq1 * 4];
        }
        // ---------------- softmax (normalization deferred) ----------------
        {
            int ii = wave;
            int i = i0 + ii;
            float m = -1e30f;
            for (int j = lane; j <= i; j += 64) m = fmaxf(m, ss[ii][j]);
            for (int off = 32; off; off >>= 1) m = fmaxf(m, __shfl_xor(m, off));
            float sum = 0.f;
            for (int j = lane; j <= i; j += 64) {
                float p = __expf(ss[ii][j] - m);
                ss[ii][j] = p;
                sum += p;
            }
            for (int off = 32; off; off >>= 1) sum += __shfl_xor(sum, off);
            if (lane == 0) sinv[ii] = 1.0f / sum;
        }

        // ---------------- Pass B: PV ----------------
        float4 acc[TI];
#pragma unroll
        for (int ii = 0; ii < TI; ++ii) acc[ii] = make_float4(0.f, 0.f, 0.f, 0.f);
        int gid = tid >> 3;        // 64 groups of 8
        int eqg = tid & 7;
        for (int jt = 0; jt < njt; ++jt) {
            int j0 = jt << 7;
            if (jt > 0) {
                __syncthreads();   // prev v-tile consumed
                for (int idx = tid; idx < JT * 8; idx += 512) {
                    int r = idx >> 3, eq = idx & 7;
                    *(float4*)&kv[r][eq * 4] =
                        *(const float4*)&vbase[(size_t)(j0 + r) * Edim + eq * 4];
                }
            }
            __syncthreads();       // jt=0: v0 + softmax visible; jt>0: staged
#pragma unroll
            for (int sub = 0; sub < 2; ++sub) {
                int jl = (sub << 6) + gid;
                int j = j0 + jl;
                float4 v4 = *(float4*)&kv[jl][eqg * 4];
                unsigned tp = st1pf[j];
#pragma unroll
                for (int ii = 0; ii < TI; ++ii) {
                    int i = i0 + ii;
                    if (j0 + (sub << 6) > i) continue;  // block-uniform skip
                    float p = (j <= i) ? ss[ii][j] : 0.f;
                    int t1 = (tp >> (ii * 4)) & 15;
                    float4 ev = *(float4*)&sevt[t1][eqg * 4];
                    acc[ii].x = fmaf(p * ev.x, v4.x, acc[ii].x);
                    acc[ii].y = fmaf(p * ev.y, v4.y, acc[ii].y);
                    acc[ii].z = fmaf(p * ev.z, v4.z, acc[ii].z);
                    acc[ii].w = fmaf(p * ev.w, v4.w, acc[ii].w);
                }
            }
        }
        // reduce across the wave's 8 groups (lane bits 3,4,5)
#pragma unroll
        for (int ii = 0; ii < TI; ++ii) {
#pragma unroll
            for (int m = 8; m <= 32; m <<= 1) {
                acc[ii].x += __shfl_xor(acc[ii].x, m);
                acc[ii].y += __shfl_xor(acc[ii].y, m);
                acc[ii].z += __shfl_xor(acc[ii].z, m);
                acc[ii].w += __shfl_xor(acc[ii].w, m);
            }
        }
        // spart overlays qm: all qm reads ended before pass A's final barrier,
        // which every wave has passed (pass-B barriers). Safe to write.
        if (lane < 8) {
#pragma unroll
            for (int ii = 0; ii < TI; ++ii)
                *(float4*)&spart[((wave * TI + ii) << 5) + lane * 4] = acc[ii];
        }
        __syncthreads();
        if (tid < TI * Edim) {
            int ii = tid >> 5, e = tid & 31;
            float yv = 0.f;
#pragma unroll
            for (int w = 0; w < 8; ++w) yv += spart[((w * TI + ii) << 5) + e];
            yv *= sinv[ii];
            y[((size_t)(b * Tdim + i0 + ii)) * Cdim + h * Edim + e] = yv;
        }
    }
}

// ---------------------------------------------------------------------------
// Kernel 3: proj GEMM (M=1024, K=256, N=256) -> d_out (B,T,C), 32x64 tiles
// ---------------------------------------------------------------------------
__global__ __launch_bounds__(256) void proj_gemm_kernel(
    const float* __restrict__ A, const float* __restrict__ Bw,
    float* __restrict__ out)
{
    const int N = Cdim;
    const int K = Cdim;
    __shared__ float As[16][34];
    __shared__ float Bs[16][64];
    int m0 = blockIdx.y * 32;
    int n0 = blockIdx.x * 64;
    int tid = threadIdx.x;
    int tr = tid >> 4, tc = tid & 15;
    float acc[2][4] = {};
    int bkr = tid >> 4, bcq = (tid & 15) * 4;

    for (int k0 = 0; k0 < K; k0 += 16) {
        if (tid < 128) {
            int r = tid >> 2, kq = (tid & 3) * 4;
            float4 av = *(const float4*)(A + (size_t)(m0 + r) * K + k0 + kq);
            As[kq + 0][r] = av.x;
            As[kq + 1][r] = av.y;
            As[kq + 2][r] = av.z;
            As[kq + 3][r] = av.w;
        }
        float4 bv = *(const float4*)(Bw + (size_t)(k0 + bkr) * N + n0 + bcq);
        *(float4*)&Bs[bkr][bcq] = bv;
        __syncthreads();
#pragma unroll
        for (int kk = 0; kk < 16; ++kk) {
            float2 a2 = *(float2*)&As[kk][tr * 2];
            float4 b4 = *(float4*)&Bs[kk][tc * 4];
            acc[0][0] = fmaf(a2.x, b4.x, acc[0][0]);
            acc[0][1] = fmaf(a2.x, b4.y, acc[0][1]);
            acc[0][2] = fmaf(a2.x, b4.z, acc[0][2]);
            acc[0][3] = fmaf(a2.x, b4.w, acc[0][3]);
            acc[1][0] = fmaf(a2.y, b4.x, acc[1][0]);
            acc[1][1] = fmaf(a2.y, b4.y, acc[1][1]);
            acc[1][2] = fmaf(a2.y, b4.z, acc[1][2]);
            acc[1][3] = fmaf(a2.y, b4.w, acc[1][3]);
        }
        __syncthreads();
    }
#pragma unroll
    for (int i = 0; i < 2; ++i) {
        int m = m0 + tr * 2 + i;
        float4 val = make_float4(acc[i][0], acc[i][1], acc[i][2], acc[i][3]);
        *(float4*)&out[(size_t)m * N + n0 + tc * 4] = val;
    }
}

// ---------------------------------------------------------------------------
extern "C" void kernel_launch(void* const* d_in, const int* in_sizes, int n_in,
                              void* d_out, int out_size, void* d_ws, size_t ws_size,
                              hipStream_t stream) {
    (void)in_sizes; (void)n_in; (void)out_size; (void)ws_size;
    const float* x = (const float*)d_in[0];
    const int* bias_matrix = (const int*)d_in[1];
    const float* w_attn = (const float*)d_in[2];
    const float* w_proj = (const float*)d_in[3];
    const float* w_edge_k = (const float*)d_in[4];
    const float* w_edge_v = (const float*)d_in[5];
    const float* edge_emb = (const float*)d_in[6];
    const float* attn_bias = (const float*)d_in[7];
    float* out = (float*)d_out;

    const size_t n_qkv = (size_t)Bdim * Hdim * Tdim * Edim;
    float* ws = (float*)d_ws;
    float* qT = ws;
    float* kT = qT + n_qkv;
    float* vT = kT + n_qkv;
    float* y = vT + n_qkv;
    float* ekt = y + (size_t)Bdim * Tdim * Cdim;
    float* evt = ekt + (size_t)NTYPES * Cdim;

    pre_kernel<<<400, 256, 0, stream>>>(x, w_attn, edge_emb, w_edge_k, w_edge_v,
                                        qT, kT, vT, ekt, evt);
    attn_kernel<<<dim3(32, 16), 512, 0, stream>>>(qT, kT, vT, bias_matrix,
                                                  ekt, evt, attn_bias, y);
    proj_gemm_kernel<<<dim3(4, 32), 256, 0, stream>>>(y, w_proj, out);
}